// Round 5
// baseline (173.720 us; speedup 1.0000x reference)
//
#include <hip/hip_runtime.h>

// qpNet: h = x @ W^T + b ; z = max(-h, -1000). x:[B,5] f32, W:[5,5], b:[5].
// B = 4194304. Memory-bound (168 MB app traffic, floor ~27 us @ 6.3 TB/s).
//
// R2: per-thread 80 B stride (5 f4/row-group)    -> 57 us (~4x line traffic/instr)
// R3: LDS-staged transpose, coalesced global     -> 50 us (barrier-phase serialization)
// R4/R5 (this): copy-shaped streaming. Thread t stores 4 contiguous f4 (16
// floats), loads an overlapping 6-f4 window [4t-1 .. 4t+4]. Row phase s = t%5
// picks one of 5 fully-static cases. No LDS, no barriers, no transpose.
// R5 fix: nontemporal builtin needs a NATIVE vector type, not HIP float4.

#define BLOCK 256

typedef float vf4 __attribute__((ext_vector_type(4)));

template <int S>
__device__ __forceinline__ void compute_case(const float* __restrict__ win,
                                             const float (&w)[5][5],
                                             const float (&bias)[5],
                                             float* __restrict__ o) {
    // Output float m (global p = 16t + m, p = 5q + S + m):
    //   row_rel = (S+m)/5, col = (S+m)%5, row starts at window offset 4-S+5*row_rel.
#pragma unroll
    for (int m = 0; m < 16; ++m) {
        const int r  = (S + m) / 5;
        const int c  = (S + m) % 5;
        const int wb = 4 - S + 5 * r;   // in [0, 19], window has 24 floats
        float h = bias[c];
#pragma unroll
        for (int i = 0; i < 5; ++i) h = fmaf(win[wb + i], w[c][i], h);
        o[m] = fmaxf(-h, -1000.0f);
    }
}

__global__ __launch_bounds__(BLOCK) void qpnet_kernel(
    const float* __restrict__ x,
    const float* __restrict__ W,
    const float* __restrict__ bfc,
    float* __restrict__ out,
    int n_threads,      // total_f4 / 4
    int total_f4)
{
    // 5x5 weights + bias in registers (uniform, L1/scalar-cached).
    float w[5][5];
    float bias[5];
#pragma unroll
    for (int j = 0; j < 5; ++j) {
        bias[j] = bfc[j];
#pragma unroll
        for (int i = 0; i < 5; ++i) w[j][i] = W[j * 5 + i];
    }

    const int t = blockIdx.x * BLOCK + threadIdx.x;
    if (t >= n_threads) return;

    const vf4* __restrict__ xin  = reinterpret_cast<const vf4*>(x);
    vf4* __restrict__       zout = reinterpret_cast<vf4*>(out);

    // Overlapping window: f4 indices 4t-1 .. 4t+4 (24 floats).
    // Clamp the two edge loads; clamped contents are provably unused:
    //   t=0 => s=0 => window floats [0..4) unused; last t => s=4 => [16..24) unused.
    float win[24];
    const int lo = 4 * t - 1;
    {
        int i0 = lo < 0 ? 0 : lo;
        int i5 = lo + 5;
        if (i5 > total_f4 - 1) i5 = total_f4 - 1;
        *reinterpret_cast<vf4*>(&win[0])  = xin[i0];
        *reinterpret_cast<vf4*>(&win[4])  = xin[lo + 1];
        *reinterpret_cast<vf4*>(&win[8])  = xin[lo + 2];
        *reinterpret_cast<vf4*>(&win[12]) = xin[lo + 3];
        *reinterpret_cast<vf4*>(&win[16]) = xin[lo + 4];
        *reinterpret_cast<vf4*>(&win[20]) = xin[i5];
    }

    float o[16];
    switch (t % 5) {        // 16 == 1 (mod 5) -> phase = t % 5
        case 0: compute_case<0>(win, w, bias, o); break;
        case 1: compute_case<1>(win, w, bias, o); break;
        case 2: compute_case<2>(win, w, bias, o); break;
        case 3: compute_case<3>(win, w, bias, o); break;
        default: compute_case<4>(win, w, bias, o); break;
    }

    // 4 contiguous, coalesced, nontemporal f4 stores (out is write-once).
    const int ob = 4 * t;
    __builtin_nontemporal_store(*reinterpret_cast<vf4*>(&o[0]),  &zout[ob + 0]);
    __builtin_nontemporal_store(*reinterpret_cast<vf4*>(&o[4]),  &zout[ob + 1]);
    __builtin_nontemporal_store(*reinterpret_cast<vf4*>(&o[8]),  &zout[ob + 2]);
    __builtin_nontemporal_store(*reinterpret_cast<vf4*>(&o[12]), &zout[ob + 3]);
}

extern "C" void kernel_launch(void* const* d_in, const int* in_sizes, int n_in,
                              void* d_out, int out_size, void* d_ws, size_t ws_size,
                              hipStream_t stream) {
    const float* x   = (const float*)d_in[0];   // [B,5]
    const float* W   = (const float*)d_in[1];   // [5,5]
    const float* bfc = (const float*)d_in[2];   // [5]
    float* out = (float*)d_out;                 // [B,5]

    int total_f4  = in_sizes[0] / 4;            // 5,242,880
    int n_threads = total_f4 / 4;               // 1,310,720
    int grid = (n_threads + BLOCK - 1) / BLOCK; // 5120

    qpnet_kernel<<<grid, BLOCK, 0, stream>>>(x, W, bfc, out, n_threads, total_f4);
}

// Round 6
// 151.190 us; speedup vs baseline: 1.1490x; 1.1490x over previous
//
#include <hip/hip_runtime.h>

// qpNet: h = x @ W^T + b ; z = max(-h, -1000). x:[B,5] f32, W:[5,5], b:[5].
// B = 4194304. Memory-bound: 168 MB app traffic, floor ~27 us @ 6.3 TB/s.
//
// R2: 80 B lane stride                -> 57 us (64 lines/instr, 16 B used each)
// R3: LDS transpose + __syncthreads   -> 50 us (barrier vmcnt(0) drain per tile)
// R5: 64 B lane stride + nontemporal  -> 82 us (WRITE_SIZE 1.76x: nt defeats
//     L2 write-combining of partial-line stores; lane stride still wrong)
// R6 (this): WAVE-PRIVATE LDS transpose. All global accesses lane-contiguous
// (idx = base + lane, 16 B lane stride -> full-line instructions). Each wave
// owns a 5 KB LDS region; all exchange is intra-wave -> NO __syncthreads.
// SIMD lockstep + lgkmcnt ordering make it correct; waves stream freely.

#define BLOCK 256
#define WAVES_PER_BLOCK 4          // BLOCK / 64
#define F4_PER_WAVE 320            // 64 lanes * 5 f4 = 1280 floats = 256 rows

typedef float vf4 __attribute__((ext_vector_type(4)));

__global__ __launch_bounds__(BLOCK) void qpnet_kernel(
    const float* __restrict__ x,
    const float* __restrict__ W,
    const float* __restrict__ bfc,
    float* __restrict__ out,
    int total_f4)
{
    __shared__ __align__(16) float lds[BLOCK * 20];   // 20 KB: 5 KB per wave

    // 5x5 weights + bias in registers (wave-uniform, scalar-cached).
    float w[5][5];
    float bias[5];
#pragma unroll
    for (int j = 0; j < 5; ++j) {
        bias[j] = bfc[j];
#pragma unroll
        for (int i = 0; i < 5; ++i) w[j][i] = W[j * 5 + i];
    }

    const int wave = threadIdx.x >> 6;
    const int lane = threadIdx.x & 63;
    float* __restrict__ wlds = &lds[wave * (64 * 20)];   // this wave's 1280 floats

    const int wave_id = blockIdx.x * WAVES_PER_BLOCK + wave;
    const int wbase = wave_id * F4_PER_WAVE;             // f4 units; fits int
    if (wbase >= total_f4) return;                       // (exact division: B*5/4 % 320 == 0)

    const vf4* __restrict__ xin  = reinterpret_cast<const vf4*>(x);
    vf4* __restrict__       zout = reinterpret_cast<vf4*>(out);

    // ---- stage in: 5 lane-contiguous global f4 loads -> LDS (stride-4-word, conflict-free)
#pragma unroll
    for (int k = 0; k < 5; ++k) {
        *reinterpret_cast<vf4*>(&wlds[(k * 64 + lane) * 4]) = xin[wbase + k * 64 + lane];
    }
    // Intra-wave ordering: lanes read words written by other lanes of the SAME
    // wave. SIMD lockstep orders the instructions; ensure lgkmcnt drain + stop
    // compiler reordering across the exchange.
    asm volatile("s_waitcnt lgkmcnt(0)" ::: "memory");

    // ---- transposed read: own 20 consecutive floats = 4 complete rows
    // (word addr lane*20 + 4p: stride-20 f4 groups cover all 32 banks per 8 lanes)
    float v[20];
#pragma unroll
    for (int p = 0; p < 5; ++p) {
        *reinterpret_cast<vf4*>(&v[4 * p]) =
            *reinterpret_cast<const vf4*>(&wlds[lane * 20 + 4 * p]);
    }

    // ---- compute: 4 rows x (5x5 matvec + bias + clamp), in place
#pragma unroll
    for (int k = 0; k < 4; ++k) {
        float t0 = bias[0], t1 = bias[1], t2 = bias[2], t3 = bias[3], t4 = bias[4];
#pragma unroll
        for (int i = 0; i < 5; ++i) {
            const float xv = v[k * 5 + i];
            t0 = fmaf(xv, w[0][i], t0);
            t1 = fmaf(xv, w[1][i], t1);
            t2 = fmaf(xv, w[2][i], t2);
            t3 = fmaf(xv, w[3][i], t3);
            t4 = fmaf(xv, w[4][i], t4);
        }
        v[k * 5 + 0] = fmaxf(-t0, -1000.0f);
        v[k * 5 + 1] = fmaxf(-t1, -1000.0f);
        v[k * 5 + 2] = fmaxf(-t2, -1000.0f);
        v[k * 5 + 3] = fmaxf(-t3, -1000.0f);
        v[k * 5 + 4] = fmaxf(-t4, -1000.0f);
    }

    // ---- transposed write back to own region
#pragma unroll
    for (int p = 0; p < 5; ++p) {
        *reinterpret_cast<vf4*>(&wlds[lane * 20 + 4 * p]) =
            *reinterpret_cast<const vf4*>(&v[4 * p]);
    }
    asm volatile("s_waitcnt lgkmcnt(0)" ::: "memory");

    // ---- stage out: LDS -> 5 lane-contiguous global f4 stores (cached: let L2 merge)
#pragma unroll
    for (int k = 0; k < 5; ++k) {
        zout[wbase + k * 64 + lane] =
            *reinterpret_cast<const vf4*>(&wlds[(k * 64 + lane) * 4]);
    }
}

extern "C" void kernel_launch(void* const* d_in, const int* in_sizes, int n_in,
                              void* d_out, int out_size, void* d_ws, size_t ws_size,
                              hipStream_t stream) {
    const float* x   = (const float*)d_in[0];   // [B,5]
    const float* W   = (const float*)d_in[1];   // [5,5]
    const float* bfc = (const float*)d_in[2];   // [5]
    float* out = (float*)d_out;                 // [B,5]

    int total_f4 = in_sizes[0] / 4;             // 5,242,880
    int n_waves  = (total_f4 + F4_PER_WAVE - 1) / F4_PER_WAVE;        // 16384
    int grid     = (n_waves + WAVES_PER_BLOCK - 1) / WAVES_PER_BLOCK; // 4096

    qpnet_kernel<<<grid, BLOCK, 0, stream>>>(x, W, bfc, out, total_f4);
}